// Round 13
// baseline (659.991 us; speedup 1.0000x reference)
//
#include <hip/hip_runtime.h>
#include <hip/hip_bf16.h>
#include <stdint.h>

// Problem constants
#define NB   2
#define NH   64
#define NHK  8
#define SQ   1024
#define SK   1024
#define DH   128
#define HID  8192     // NH*DH
#define MROWS 2048    // NB*SQ
#define NT   128      // GEMM K-tiles: 8192/64

typedef unsigned short u16;
typedef __bf16 bf16_t;
typedef bf16_t bf16x8 __attribute__((ext_vector_type(8)));
typedef float  f32x4  __attribute__((ext_vector_type(4)));
typedef u16    u16x8  __attribute__((ext_vector_type(8)));
typedef u16    u16x4  __attribute__((ext_vector_type(4)));
typedef uint32_t u32x4 __attribute__((ext_vector_type(4)));

#define DEV __device__ __forceinline__

DEV u16 f2bf(float f) {
  uint32_t u = __builtin_bit_cast(uint32_t, f);
  u += 0x7fffu + ((u >> 16) & 1u);   // RNE
  return (u16)(u >> 16);
}

DEV float bf2f(u16 u) {
  return __builtin_bit_cast(float, (uint32_t)u << 16);
}

DEV bf16x8 pack8(const float* v) {
  u16x8 r;
#pragma unroll
  for (int i = 0; i < 8; ++i) r[i] = f2bf(v[i]);
  return __builtin_bit_cast(bf16x8, r);
}

DEV f32x4 mfma16(bf16x8 a, bf16x8 b, f32x4 c) {
  return __builtin_amdgcn_mfma_f32_16x16x32_bf16(a, b, c, 0, 0, 0);
}

// async global->LDS, 16B per lane; lds dest must be wave-uniform base
DEV void gload_lds16(const void* g, void* l) {
  __builtin_amdgcn_global_load_lds(
      (const __attribute__((address_space(1))) void*)g,
      (__attribute__((address_space(3))) void*)l, 16, 0, 0);
}

#define BAR()  asm volatile("s_barrier" ::: "memory")
#define VMC(n) asm volatile("s_waitcnt vmcnt(" #n ")" ::: "memory")

// ---------------------------------------------------------------------------
// Kernel A (prep, all pure HBM streaming):
//   blocks [0,16384):      wo fp32 [K][N] -> Wt bf16 [N][K] (transpose;
//                          f32 LDS tile padded +1 => 2-way banks, free)
//   blocks [16384,17408):  keys -> Kf fragment-major bf16
//   blocks [17408,18432):  values -> Vf fragment-major bf16
//   blocks [18432,19456):  mask fp32 -> Mf WAVE-FRAGMENT-MAJOR bf16,
//                          pre-scaled by log2(e). One (mi,ni) attn read =
//                          one coalesced 512B wave load.
// ---------------------------------------------------------------------------
__global__ __launch_bounds__(256) void k_prep(
    const float* __restrict__ wo, u16* __restrict__ wt,
    const float* __restrict__ keys, char* __restrict__ kf,
    const float* __restrict__ values, char* __restrict__ vf,
    const float* __restrict__ mask, char* __restrict__ mf) {
  __shared__ float tile[64][65];
  const int bid = blockIdx.x;
  const int tid = threadIdx.x;

  if (bid < 16384) {
    // ---- wo transpose ----
    const int k0 = (bid & 127) * 64;
    const int n0 = (bid >> 7) * 64;
    const int r  = tid >> 4, cg = tid & 15;
#pragma unroll
    for (int p = 0; p < 4; ++p) {
      int row = r + p * 16;  // k-local
      float4 v = *(const float4*)(wo + (size_t)(k0 + row) * 8192 + n0 + cg * 4);
      *(float4*)&tile[row][cg * 4] = v;
    }
    __syncthreads();
#pragma unroll
    for (int p = 0; p < 4; ++p) {
      int row = r + p * 16;  // n-local
      u16x4 ov;
      ov[0] = f2bf(tile[cg * 4 + 0][row]);
      ov[1] = f2bf(tile[cg * 4 + 1][row]);
      ov[2] = f2bf(tile[cg * 4 + 2][row]);
      ov[3] = f2bf(tile[cg * 4 + 3][row]);
      *(u16x4*)(wt + (size_t)(n0 + row) * 8192 + k0 + cg * 4) = ov;
    }
  } else if (bid < 17408) {
    // ---- K -> fragment-major (lane l: K[t*64+ni*16+(l&15)][c*32+(l>>4)*8+j])
    int g = (bid - 16384) * 256 + tid;
    int l    = g & 63;
    int blk  = (g >> 6) & 15;
    int t    = (g >> 10) & 15;
    int head = g >> 14;
    int ni = blk >> 2, c = blk & 3;
    int row = t * 64 + ni * 16 + (l & 15);
    int col = c * 32 + (l >> 4) * 8;
    const float* src = keys + ((size_t)head * 1024 + row) * 128 + col;
    float tb[8];
    *(float4*)tb       = *(const float4*)src;
    *(float4*)(tb + 4) = *(const float4*)(src + 4);
    u16x8 r;
#pragma unroll
    for (int i = 0; i < 8; ++i) r[i] = f2bf(tb[i]);
    *(u16x8*)(kf + (size_t)g * 16) = r;
  } else if (bid < 18432) {
    // ---- V -> fragment-major (lane l: V[t*64+ks*32+(l>>4)*8+j][nd*16+(l&15)])
    int g = (bid - 17408) * 256 + tid;
    int l    = g & 63;
    int blk  = (g >> 6) & 15;
    int t    = (g >> 10) & 15;
    int head = g >> 14;
    int ks = blk >> 3, nd = blk & 7;
    int k0 = t * 64 + ks * 32 + (l >> 4) * 8;
    int d  = nd * 16 + (l & 15);
    const float* src = values + (size_t)head * 131072 + (size_t)k0 * 128 + d;
    u16x8 r;
#pragma unroll
    for (int j = 0; j < 8; ++j) r[j] = f2bf(src[j * 128]);
    *(u16x8*)(vf + (size_t)g * 16) = r;
  } else {
    // ---- mask -> wave-fragment-major bf16, pre-scaled by log2(e) ----
    const float L2E = 1.4426950408889634f;
    int bid2 = bid - 18432;          // (b, qc, t)
    int bq = bid2 >> 9;
    int qc = (bid2 >> 4) & 31;
    int tt = bid2 & 15;
    int ni = tid >> 6, l = tid & 63;
#pragma unroll
    for (int mi = 0; mi < 2; ++mi) {
      int row = qc * 32 + mi * 16 + (l & 15);
      int col = tt * 64 + ni * 16 + (l >> 4) * 4;
      float4 v = *(const float4*)(mask + ((size_t)bq * 1024 + row) * 1024 + col);
      u16x4 r;
      r[0] = f2bf(v.x * L2E);
      r[1] = f2bf(v.y * L2E);
      r[2] = f2bf(v.z * L2E);
      r[3] = f2bf(v.w * L2E);
      *(u16x4*)(mf + ((((size_t)bq * 32 + qc) * 16 + tt) * 8 + mi * 4 + ni) * 512
                + (size_t)l * 8) = r;
    }
  }
}

// ---------------------------------------------------------------------------
// Kernel B: flash attention, 8 waves (512 thr), QBLK=256 (32 q-rows/wave),
// KVBLK=64. 2-deep KV ring via global_load_lds, vmcnt(0)+BAR per tile
// (R8-verified). P stays IN REGISTERS: softmax packs P to bf16 pairs
// (pkx/pky[mi][ni]); PV A-fragments are built with 32 __shfl + 16 selects
// per tile (word t of lane(lr,lg) = pk[ni=ks*2+(lg>>1)] from source lane
// lr + 32*(lg&1) + 16*(t>>1); runtime-ni resolved by dual-shfl + cndmask).
// LDS = 2x16K (K) + 2x16K (V) = 64KB -> 2 blocks/CU at VGPR<=128
// (__launch_bounds__(512,4)) = 4 waves/SIMD (2x the TLP of R12).
// ---------------------------------------------------------------------------
__global__ __launch_bounds__(512, 4) void k_attn(
    const float* __restrict__ xq, const char* __restrict__ kf_g,
    const char* __restrict__ vf_g, const char* __restrict__ maskf,
    u16* __restrict__ abf) {
  __shared__ char kbuf[2][16384];
  __shared__ char vbuf[2][16384];
  // XCD-chunked: 64 consecutive logical blocks per XCD (16 heads x 4 q-chunks)
  const int bid = (blockIdx.x & 7) * 64 + (blockIdx.x >> 3);
  const int tid = threadIdx.x;

  const int b = bid >> 8;
  const int h = (bid >> 2) & 63;
  const int q0 = (bid & 3) * 256;
  const int hk = h >> 3;
  const int w = tid >> 6, l = tid & 63;
  const int lr = l & 15, lg = l >> 4;

  // Q fragments (B-operand: n=q-row=l&15, k=(l>>4)*8+j per 32-chunk)
  bf16x8 qf[2][4];
  {
    const float* qb = xq + (((size_t)(b * NH + h) * SQ) + q0 + w * 32) * DH;
#pragma unroll
    for (int mi = 0; mi < 2; ++mi)
#pragma unroll
      for (int c = 0; c < 4; ++c) {
        const float* qp = qb + (size_t)(mi * 16 + lr) * DH + c * 32 + lg * 8;
        float t[8];
        *(float4*)t       = *(const float4*)qp;
        *(float4*)(t + 4) = *(const float4*)(qp + 4);
        qf[mi][c] = pack8(t);
      }
  }

  f32x4 o[2][8];
#pragma unroll
  for (int mi = 0; mi < 2; ++mi)
#pragma unroll
    for (int nd = 0; nd < 8; ++nd) o[mi][nd] = (f32x4){0.f, 0.f, 0.f, 0.f};
  float mrun[2] = {-1e30f, -1e30f}, lrun[2] = {0.f, 0.f};

  const char* kf_h = kf_g + (size_t)(b * NHK + hk) * 262144;
  const char* vf_h = vf_g + (size_t)(b * NHK + hk) * 262144;
  // wave-fragment-major mask: qc = q0/32 + w
  const char* mk0 = maskf +
      ((size_t)(b * 32 + (bid & 3) * 8 + w) * 16) * 4096 + (size_t)l * 8;
  // log2-domain softmax: SCALE2 = (1/sqrt(128)) * log2(e); mask pre-scaled.
  const float SCALE2 = 0.08838834764831845f * 1.4426950408889634f;

  // stage this wave's 2KB share of fragment-major tile tt into dst
#define STG(src, tt, dst) do {                                                 \
    const char* s_ = (src) + (((tt) & 15) * 16384);                            \
    _Pragma("unroll")                                                          \
    for (int j_ = 0; j_ < 2; ++j_)                                             \
      gload_lds16(s_ + (w * 2 + j_) * 1024 + l * 16,                           \
                  (dst) + (w * 2 + j_) * 1024);                                \
  } while (0)

  // prologue: tile 0 into buf0
  STG(kf_h, 0, kbuf[0]);
  STG(vf_h, 0, vbuf[0]);
  VMC(0);
  BAR();

  const int s0 = lr + ((lg & 1) << 5);   // shfl source lanes for PV frags
  const int s1 = s0 + 16;
  const bool hi_ni = ((lg >> 1) & 1) != 0;

  for (int t = 0; t < 16; ++t) {
    const int cur = t & 1;
    // ---- mask prefetch FIRST: 8 coalesced 512B wave loads ----
    u16x4 mpre[2][4];
#pragma unroll
    for (int mi = 0; mi < 2; ++mi)
#pragma unroll
      for (int ni = 0; ni < 4; ++ni)
        mpre[mi][ni] =
            *(const u16x4*)(mk0 + (size_t)(t * 8 + mi * 4 + ni) * 512);

    // ---- stage tile t+1 into the other ring slot ----
    STG(kf_h, t + 1, kbuf[cur ^ 1]);
    STG(vf_h, t + 1, vbuf[cur ^ 1]);

    // ---- QK^T swapped: S^T[kpos][q]; lane: q=lr, kpos=ni*16+lg*4+r ----
    f32x4 st[2][4];
#pragma unroll
    for (int mi = 0; mi < 2; ++mi)
#pragma unroll
      for (int ni = 0; ni < 4; ++ni) st[mi][ni] = (f32x4){0.f, 0.f, 0.f, 0.f};
#pragma unroll
    for (int ni = 0; ni < 4; ++ni)
#pragma unroll
      for (int c = 0; c < 4; ++c) {
        bf16x8 kfr = *(const bf16x8*)(kbuf[cur] + (ni * 4 + c) * 1024 + l * 16);
        st[0][ni] = mfma16(kfr, qf[0][c], st[0][ni]);
        st[1][ni] = mfma16(kfr, qf[1][c], st[1][ni]);
      }

    // ---- softmax (log2 domain): per-lane q-row; P packed to registers ----
    uint32_t pkx[2][4], pky[2][4];
#pragma unroll
    for (int mi = 0; mi < 2; ++mi) {
      float x[4][4];
#pragma unroll
      for (int ni = 0; ni < 4; ++ni)
#pragma unroll
        for (int r = 0; r < 4; ++r)
          x[ni][r] = st[mi][ni][r] * SCALE2 + bf2f(mpre[mi][ni][r]);
      float v = fmaxf(fmaxf(x[0][0], x[0][1]), fmaxf(x[0][2], x[0][3]));
#pragma unroll
      for (int ni = 1; ni < 4; ++ni)
        v = fmaxf(v, fmaxf(fmaxf(x[ni][0], x[ni][1]),
                           fmaxf(x[ni][2], x[ni][3])));
      v = fmaxf(v, __shfl_xor(v, 16));
      v = fmaxf(v, __shfl_xor(v, 32));
      // defer-max (threshold 8 nats = 11.54 log2-units)
      if (__any(v > mrun[mi] + 11.5f)) {
        float mnew = fmaxf(mrun[mi], v);
        float fac = exp2f(mrun[mi] - mnew);
        lrun[mi] *= fac;
        mrun[mi] = mnew;
#pragma unroll
        for (int r = 0; r < 4; ++r) {
          float fr = __shfl(fac, lg * 4 + r);
#pragma unroll
          for (int nd = 0; nd < 8; ++nd) o[mi][nd][r] *= fr;
        }
      }
      float rs = 0.f;
#pragma unroll
      for (int ni = 0; ni < 4; ++ni) {
        float p0 = exp2f(x[ni][0] - mrun[mi]);
        float p1 = exp2f(x[ni][1] - mrun[mi]);
        float p2 = exp2f(x[ni][2] - mrun[mi]);
        float p3 = exp2f(x[ni][3] - mrun[mi]);
        rs += (p0 + p1) + (p2 + p3);
        pkx[mi][ni] = (uint32_t)f2bf(p0) | ((uint32_t)f2bf(p1) << 16);
        pky[mi][ni] = (uint32_t)f2bf(p2) | ((uint32_t)f2bf(p3) << 16);
      }
      rs += __shfl_xor(rs, 16);
      rs += __shfl_xor(rs, 32);
      lrun[mi] += rs;
    }

    // ---- PV: O += P[32x64] * V[64x128]; P-frags built via shfl ----
#pragma unroll
    for (int ks = 0; ks < 2; ++ks) {
      bf16x8 pf[2];
#pragma unroll
      for (int mi = 0; mi < 2; ++mi) {
        uint32_t a0 = __shfl(pkx[mi][ks * 2 + 0], s0);
        uint32_t b0 = __shfl(pkx[mi][ks * 2 + 1], s0);
        uint32_t a1 = __shfl(pky[mi][ks * 2 + 0], s0);
        uint32_t b1 = __shfl(pky[mi][ks * 2 + 1], s0);
        uint32_t a2 = __shfl(pkx[mi][ks * 2 + 0], s1);
        uint32_t b2 = __shfl(pkx[mi][ks * 2 + 1], s1);
        uint32_t a3 = __shfl(pky[mi][ks * 2 + 0], s1);
        uint32_t b3 = __shfl(pky[mi][ks * 2 + 1], s1);
        u32x4 fw;
        fw[0] = hi_ni ? b0 : a0;
        fw[1] = hi_ni ? b1 : a1;
        fw[2] = hi_ni ? b2 : a2;
        fw[3] = hi_ni ? b3 : a3;
        pf[mi] = __builtin_bit_cast(bf16x8, fw);
      }
#pragma unroll
      for (int nd = 0; nd < 8; ++nd) {
        bf16x8 vfr = *(const bf16x8*)(vbuf[cur] + (ks * 8 + nd) * 1024 + l * 16);
        o[0][nd] = mfma16(pf[0], vfr, o[0][nd]);
        o[1][nd] = mfma16(pf[1], vfr, o[1][nd]);
      }
    }

    // ---- fence: drain stages (t+1 tile ready), barrier publishes ----
    VMC(0);
    BAR();
  }
#undef STG

  // ---- epilogue: normalize (lrun via shfl), write bf16 A ----
#pragma unroll
  for (int mi = 0; mi < 2; ++mi) {
    float inv[4];
#pragma unroll
    for (int r = 0; r < 4; ++r) inv[r] = 1.0f / __shfl(lrun[mi], lg * 4 + r);
#pragma unroll
    for (int nd = 0; nd < 8; ++nd)
#pragma unroll
      for (int r = 0; r < 4; ++r) {
        int grow = q0 + w * 32 + mi * 16 + lg * 4 + r;
        size_t m = (size_t)b * SQ + grow;
        int col = h * DH + nd * 16 + lr;
        abf[m * HID + col] = f2bf(o[mi][nd][r] * inv[r]);
      }
  }
}

// ---------------------------------------------------------------------------
// Kernel C: C[2048][8192] = A[2048][8192]bf16 · Wt[8192][8192]^T bf16
// 256x256 tile, BK=64, 8 waves (2Mx4N), 8-phase counted-vmcnt schedule,
// T2 swizzle, setprio, XCD-swizzled grid. (Unchanged: 50% MfmaUtil.)
// ---------------------------------------------------------------------------
__global__ __launch_bounds__(512, 2) void k_gemm(const u16* __restrict__ A,
                                                 const u16* __restrict__ Bt,
                                                 float* __restrict__ C) {
  __shared__ char L[131072];
  const int bid = blockIdx.x;
  const int logical = (bid & 7) * 32 + (bid >> 3);
  const int m0 = (logical & 7) * 256;
  const int n0 = (logical >> 3) * 256;
  const int tid = threadIdx.x;
  const int w = tid >> 6, l = tid & 63;
  const int lr = l & 15, lg = l >> 4;
  const int wm = w >> 2, wn = w & 3;   // 2M x 4N

  int srow[2], scol[2];
#pragma unroll
  for (int j = 0; j < 2; ++j) {
    int ch = j * 512 + tid;
    srow[j] = ch >> 3;
    scol[j] = (ch & 7) ^ (srow[j] & 7);
  }

  const char* Ab = (const char*)A;
  const char* Bb = (const char*)Bt;

#define STAGE(gb, row0, tt, dst) do {                                          \
    int kt_ = ((tt) < NT ? (tt) : 0) * 64;                                     \
    _Pragma("unroll")                                                          \
    for (int j_ = 0; j_ < 2; ++j_)                                             \
      gload_lds16((gb) + ((size_t)((row0) + srow[j_]) * 8192 + kt_ +           \
                          scol[j_] * 8) * 2,                                   \
                  (dst) + j_ * 8192 + (w << 10));                              \
  } while (0)

#define LDA(base, hs) do {                                                     \
    _Pragma("unroll")                                                          \
    for (int mi_ = 0; mi_ < 4; ++mi_) {                                        \
      int r_ = wm * 64 + mi_ * 16 + lr;                                        \
      _Pragma("unroll")                                                        \
      for (int ks_ = 0; ks_ < 2; ++ks_)                                        \
        bA[mi_][ks_] = *(const bf16x8*)(L + (base) + (hs) * 16384 + r_ * 128 + \
                        ((ks_ * 64 + lg * 16) ^ ((r_ & 7) << 4)));             \
    }                                                                          \
  } while (0)

#define LDB(dst, base, hs) do {                                                \
    _Pragma("unroll")                                                          \
    for (int ni_ = 0; ni_ < 2; ++ni_) {                                        \
      int r_ = wn * 32 + ni_ * 16 + lr;                                        \
      _Pragma("unroll")                                                        \
      for (int ks_ = 0; ks_ < 2; ++ks_)                                        \
        dst[ni_][ks_] = *(const bf16x8*)(L + (base) + 32768 + (hs) * 16384 +   \
                        r_ * 128 + ((ks_ * 64 + lg * 16) ^ ((r_ & 7) << 4)));  \
    }                                                                          \
  } while (0)

#define MM(mh, nh, BB) do {                                                    \
    __builtin_amdgcn_s_setprio(1);                                             \
    _Pragma("unroll")                                                          \
    for (int mi_ = 0; mi_ < 4; ++mi_)                                          \
      _Pragma("unroll")                                                        \
      for (int ni_ = 0; ni_ < 2; ++ni_)                                        \
        _Pragma("unroll")                                                      \
        for (int ks_ = 0; ks_ < 2; ++ks_)                                      \
          acc[mh][nh][mi_][ni_] =                                              \
              mfma16(bA[mi_][ks_], BB[ni_][ks_], acc[mh][nh][mi_][ni_]);       \
    __builtin_amdgcn_s_setprio(0);                                             \
  } while (0)

  f32x4 acc[2][2][4][2];
#pragma unroll
  for (int a1 = 0; a1 < 2; ++a1)
#pragma unroll
    for (int a2 = 0; a2 < 2; ++a2)
#pragma unroll
      for (int a3 = 0; a3 < 4; ++a3)
#pragma unroll
        for (int a4 = 0; a4 < 2; ++a4)
          acc[a1][a2][a3][a4] = (f32x4){0.f, 0.f, 0.f, 0.f};

  bf16x8 bA[4][2], bB0[2][2], bB1[2][2];

  STAGE(Ab, m0,       0, L + 0);
  STAGE(Bb, n0,       0, L + 32768);
  STAGE(Bb, n0 + 128, 0, L + 49152);
  STAGE(Ab, m0 + 128, 0, L + 16384);
  STAGE(Ab, m0,       1, L + 65536);
  STAGE(Bb, n0,       1, L + 65536 + 32768);
  STAGE(Bb, n0 + 128, 1, L + 65536 + 49152);
  VMC(6);
  BAR();

  for (int t = 0; t < NT; ++t) {
    const int c  = (t & 1) << 16;
    const int cn = c ^ 65536;
    STAGE(Ab, m0 + 128, t + 1, L + cn + 16384);
    LDA(c, 0);
    LDB(bB0, c, 0);
    BAR();
    MM(0, 0, bB0);
    BAR();
    STAGE(Ab, m0, t + 2, L + c + 0);
    LDB(bB1, c, 1);
    BAR();
    MM(0, 1, bB1);
    BAR();
    STAGE(Bb, n0, t + 2, L + c + 32768);
    LDA(c, 1);
    BAR();
    MM(1, 1, bB1);
    BAR();
    STAGE(Bb, n0 + 128, t + 2, L + c + 49152);
    BAR();
    MM(1, 0, bB0);
    VMC(6);
    BAR();
  }
  VMC(0);

#pragma unroll
  for (int mh = 0; mh < 2; ++mh)
#pragma unroll
    for (int nh = 0; nh < 2; ++nh)
#pragma unroll
      for (int mi = 0; mi < 4; ++mi)
#pragma unroll
        for (int ni = 0; ni < 2; ++ni)
#pragma unroll
          for (int rr = 0; rr < 4; ++rr)
            C[(size_t)(m0 + mh * 128 + wm * 64 + mi * 16 + lg * 4 + rr) * 8192 +
              n0 + nh * 128 + wn * 32 + ni * 16 + lr] = acc[mh][nh][mi][ni][rr];
#undef STAGE
#undef LDA
#undef LDB
#undef MM
}

// ---------------------------------------------------------------------------
extern "C" void kernel_launch(void* const* d_in, const int* in_sizes, int n_in,
                              void* d_out, int out_size, void* d_ws, size_t ws_size,
                              hipStream_t stream) {
  const float* xq     = (const float*)d_in[0];
  const float* keys   = (const float*)d_in[1];
  const float* values = (const float*)d_in[2];
  const float* mask   = (const float*)d_in[3];
  const float* wo     = (const float*)d_in[4];
  float* out = (float*)d_out;

  // ws layout (168 MiB):
  //   [0, 32Mi)        A bf16 (attn out, [2048][8192])
  //   [32Mi, 160Mi)    Wt bf16 (wo^T, [8192][8192])
  //   [+4Mi][+4Mi]     Kf / Vf bf16 fragment-major
  // Mask bf16 (4 MiB, wave-fragment-major, pre-scaled by log2e) lives in the
  // LAST 4 MiB of d_out: written by k_prep, read by k_attn, then overwritten
  // by k_gemm's output.
  char* ws = (char*)d_ws;
  u16*  Abf = (u16*)ws;
  u16*  Wt  = (u16*)(ws + 33554432ull);
  char* Kf  = ws + 33554432ull + 134217728ull;
  char* Vf  = Kf + 4194304ull;
  char* Mf  = (char*)d_out + 62914560ull;  // 60 MiB offset

  hipLaunchKernelGGL(k_prep, dim3(19456), dim3(256), 0, stream,
                     wo, Wt, keys, Kf, values, Vf, mask, Mf);
  hipLaunchKernelGGL(k_attn, dim3(512), dim3(512), 0, stream,
                     xq, Kf, Vf, Mf, Abf);
  hipLaunchKernelGGL(k_gemm, dim3(256), dim3(512), 0, stream, Abf, Wt, out);
}

// Round 14
// 460.301 us; speedup vs baseline: 1.4338x; 1.4338x over previous
//
#include <hip/hip_runtime.h>
#include <hip/hip_bf16.h>
#include <stdint.h>

// Problem constants
#define NB   2
#define NH   64
#define NHK  8
#define SQ   1024
#define SK   1024
#define DH   128
#define HID  8192     // NH*DH
#define MROWS 2048    // NB*SQ
#define NT   128      // GEMM K-tiles: 8192/64

typedef unsigned short u16;
typedef __bf16 bf16_t;
typedef bf16_t bf16x8 __attribute__((ext_vector_type(8)));
typedef float  f32x4  __attribute__((ext_vector_type(4)));
typedef u16    u16x8  __attribute__((ext_vector_type(8)));
typedef u16    u16x4  __attribute__((ext_vector_type(4)));

#define DEV __device__ __forceinline__

DEV u16 f2bf(float f) {
  uint32_t u = __builtin_bit_cast(uint32_t, f);
  u += 0x7fffu + ((u >> 16) & 1u);   // RNE
  return (u16)(u >> 16);
}

DEV float bf2f(u16 u) {
  return __builtin_bit_cast(float, (uint32_t)u << 16);
}

DEV bf16x8 pack8(const float* v) {
  u16x8 r;
#pragma unroll
  for (int i = 0; i < 8; ++i) r[i] = f2bf(v[i]);
  return __builtin_bit_cast(bf16x8, r);
}

DEV f32x4 mfma16(bf16x8 a, bf16x8 b, f32x4 c) {
  return __builtin_amdgcn_mfma_f32_16x16x32_bf16(a, b, c, 0, 0, 0);
}

// async global->LDS, 16B per lane; lds dest must be wave-uniform base
DEV void gload_lds16(const void* g, void* l) {
  __builtin_amdgcn_global_load_lds(
      (const __attribute__((address_space(1))) void*)g,
      (__attribute__((address_space(3))) void*)l, 16, 0, 0);
}

#define BAR()  asm volatile("s_barrier" ::: "memory")
#define VMC(n) asm volatile("s_waitcnt vmcnt(" #n ")" ::: "memory")

// ---------------------------------------------------------------------------
// Kernel A (prep, all pure HBM streaming):
//   blocks [0,16384):      wo fp32 [K][N] -> Wt bf16 [N][K] (transpose;
//                          f32 LDS tile padded +1 => 2-way banks, free)
//   blocks [16384,17408):  keys -> Kf fragment-major bf16
//   blocks [17408,18432):  values -> Vf fragment-major bf16
//   blocks [18432,19456):  mask fp32 -> Mf WAVE-FRAGMENT-MAJOR bf16,
//                          pre-scaled by log2(e). One (mi,ni) attn read =
//                          one coalesced 512B wave load.
// ---------------------------------------------------------------------------
__global__ __launch_bounds__(256) void k_prep(
    const float* __restrict__ wo, u16* __restrict__ wt,
    const float* __restrict__ keys, char* __restrict__ kf,
    const float* __restrict__ values, char* __restrict__ vf,
    const float* __restrict__ mask, char* __restrict__ mf) {
  __shared__ float tile[64][65];
  const int bid = blockIdx.x;
  const int tid = threadIdx.x;

  if (bid < 16384) {
    // ---- wo transpose ----
    const int k0 = (bid & 127) * 64;
    const int n0 = (bid >> 7) * 64;
    const int r  = tid >> 4, cg = tid & 15;
#pragma unroll
    for (int p = 0; p < 4; ++p) {
      int row = r + p * 16;  // k-local
      float4 v = *(const float4*)(wo + (size_t)(k0 + row) * 8192 + n0 + cg * 4);
      *(float4*)&tile[row][cg * 4] = v;
    }
    __syncthreads();
#pragma unroll
    for (int p = 0; p < 4; ++p) {
      int row = r + p * 16;  // n-local
      u16x4 ov;
      ov[0] = f2bf(tile[cg * 4 + 0][row]);
      ov[1] = f2bf(tile[cg * 4 + 1][row]);
      ov[2] = f2bf(tile[cg * 4 + 2][row]);
      ov[3] = f2bf(tile[cg * 4 + 3][row]);
      *(u16x4*)(wt + (size_t)(n0 + row) * 8192 + k0 + cg * 4) = ov;
    }
  } else if (bid < 17408) {
    // ---- K -> fragment-major (lane l: K[t*64+ni*16+(l&15)][c*32+(l>>4)*8+j])
    int g = (bid - 16384) * 256 + tid;
    int l    = g & 63;
    int blk  = (g >> 6) & 15;
    int t    = (g >> 10) & 15;
    int head = g >> 14;
    int ni = blk >> 2, c = blk & 3;
    int row = t * 64 + ni * 16 + (l & 15);
    int col = c * 32 + (l >> 4) * 8;
    const float* src = keys + ((size_t)head * 1024 + row) * 128 + col;
    float tb[8];
    *(float4*)tb       = *(const float4*)src;
    *(float4*)(tb + 4) = *(const float4*)(src + 4);
    u16x8 r;
#pragma unroll
    for (int i = 0; i < 8; ++i) r[i] = f2bf(tb[i]);
    *(u16x8*)(kf + (size_t)g * 16) = r;
  } else if (bid < 18432) {
    // ---- V -> fragment-major (lane l: V[t*64+ks*32+(l>>4)*8+j][nd*16+(l&15)])
    int g = (bid - 17408) * 256 + tid;
    int l    = g & 63;
    int blk  = (g >> 6) & 15;
    int t    = (g >> 10) & 15;
    int head = g >> 14;
    int ks = blk >> 3, nd = blk & 7;
    int k0 = t * 64 + ks * 32 + (l >> 4) * 8;
    int d  = nd * 16 + (l & 15);
    const float* src = values + (size_t)head * 131072 + (size_t)k0 * 128 + d;
    u16x8 r;
#pragma unroll
    for (int j = 0; j < 8; ++j) r[j] = f2bf(src[j * 128]);
    *(u16x8*)(vf + (size_t)g * 16) = r;
  } else {
    // ---- mask -> wave-fragment-major bf16, pre-scaled by log2(e) ----
    const float L2E = 1.4426950408889634f;
    int bid2 = bid - 18432;          // (b, qc, t)
    int bq = bid2 >> 9;
    int qc = (bid2 >> 4) & 31;
    int tt = bid2 & 15;
    int ni = tid >> 6, l = tid & 63;
#pragma unroll
    for (int mi = 0; mi < 2; ++mi) {
      int row = qc * 32 + mi * 16 + (l & 15);
      int col = tt * 64 + ni * 16 + (l >> 4) * 4;
      float4 v = *(const float4*)(mask + ((size_t)bq * 1024 + row) * 1024 + col);
      u16x4 r;
      r[0] = f2bf(v.x * L2E);
      r[1] = f2bf(v.y * L2E);
      r[2] = f2bf(v.z * L2E);
      r[3] = f2bf(v.w * L2E);
      *(u16x4*)(mf + ((((size_t)bq * 32 + qc) * 16 + tt) * 8 + mi * 4 + ni) * 512
                + (size_t)l * 8) = r;
    }
  }
}

// ---------------------------------------------------------------------------
// Kernel B: flash attention, 8 waves (512 thr), QBLK=256 (32 q-rows/wave),
// KVBLK=64. 3-deep KV ring buffer staged via global_load_lds; counted
// vmcnt(4) end-of-tile fence (newest 4 stage-DMAs stay in flight across the
// raw s_barrier; issue-order counting proves stage(t+1) retired).
// Mask reads: ONE coalesced 512B wave load per (mi,ni) (wave-fragment-major).
// No setprio (barrier-synced lockstep waves; m190). No launch_bounds cap
// beyond 512 (R13 lesson: forcing 4 waves/EU spills ~120-reg live set).
// LDS = 3x32K (KV) + 32K (P) = 128KB.
// ---------------------------------------------------------------------------
__global__ __launch_bounds__(512) void k_attn(
    const float* __restrict__ xq, const char* __restrict__ kf_g,
    const char* __restrict__ vf_g, const char* __restrict__ maskf,
    u16* __restrict__ abf) {
  __shared__ char kbuf[3][16384];
  __shared__ char vbuf[3][16384];
  __shared__ char pls[32768];
  // XCD-chunked: 64 consecutive logical blocks per XCD (16 heads x 4 q-chunks)
  const int bid = (blockIdx.x & 7) * 64 + (blockIdx.x >> 3);
  const int tid = threadIdx.x;

  const int b = bid >> 8;
  const int h = (bid >> 2) & 63;
  const int q0 = (bid & 3) * 256;
  const int hk = h >> 3;
  const int w = tid >> 6, l = tid & 63;
  const int lr = l & 15, lg = l >> 4;
  char* pbyte = pls + w * 4096;  // per-wave P tile [32][64] bf16, swizzled

  // Q fragments (B-operand: n=q-row=l&15, k=(l>>4)*8+j per 32-chunk)
  bf16x8 qf[2][4];
  {
    const float* qb = xq + (((size_t)(b * NH + h) * SQ) + q0 + w * 32) * DH;
#pragma unroll
    for (int mi = 0; mi < 2; ++mi)
#pragma unroll
      for (int c = 0; c < 4; ++c) {
        const float* qp = qb + (size_t)(mi * 16 + lr) * DH + c * 32 + lg * 8;
        float t[8];
        *(float4*)t       = *(const float4*)qp;
        *(float4*)(t + 4) = *(const float4*)(qp + 4);
        qf[mi][c] = pack8(t);
      }
  }

  f32x4 o[2][8];
#pragma unroll
  for (int mi = 0; mi < 2; ++mi)
#pragma unroll
    for (int nd = 0; nd < 8; ++nd) o[mi][nd] = (f32x4){0.f, 0.f, 0.f, 0.f};
  float mrun[2] = {-1e30f, -1e30f}, lrun[2] = {0.f, 0.f};

  const char* kf_h = kf_g + (size_t)(b * NHK + hk) * 262144;
  const char* vf_h = vf_g + (size_t)(b * NHK + hk) * 262144;
  // wave-fragment-major mask: qc = q0/32 + w
  const char* mk0 = maskf +
      ((size_t)(b * 32 + (bid & 3) * 8 + w) * 16) * 4096 + (size_t)l * 8;
  // log2-domain softmax: SCALE2 = (1/sqrt(128)) * log2(e); mask pre-scaled.
  const float SCALE2 = 0.08838834764831845f * 1.4426950408889634f;
  const int rswz = (lr & 7) << 4;

  // stage this wave's 2KB share of fragment-major tile tt into dst
#define STG(src, tt, dst) do {                                                 \
    const char* s_ = (src) + (((tt) & 15) * 16384);                            \
    _Pragma("unroll")                                                          \
    for (int j_ = 0; j_ < 2; ++j_)                                             \
      gload_lds16(s_ + (w * 2 + j_) * 1024 + l * 16,                           \
                  (dst) + (w * 2 + j_) * 1024);                                \
  } while (0)

  // prologue: tiles 0 and 1 into buf0/buf1
  STG(kf_h, 0, kbuf[0]);
  STG(vf_h, 0, vbuf[0]);
  STG(kf_h, 1, kbuf[1]);
  STG(vf_h, 1, vbuf[1]);
  VMC(4);   // tile-0 stages retired; tile-1 may stay in flight
  BAR();

  int cur = 0;
  for (int t = 0; t < 16; ++t) {
    const int nx2 = (cur + 2 == 3) ? 0 : ((cur + 2 == 4) ? 1 : cur + 2);
    // ---- mask prefetch FIRST: 8 coalesced 512B wave loads ----
    u16x4 mpre[2][4];
#pragma unroll
    for (int mi = 0; mi < 2; ++mi)
#pragma unroll
      for (int ni = 0; ni < 4; ++ni)
        mpre[mi][ni] =
            *(const u16x4*)(mk0 + (size_t)(t * 8 + mi * 4 + ni) * 512);

    // ---- stage tile t+2 into buf[(t+2)%3] (freed at end of iter t-1) ----
    STG(kf_h, t + 2, kbuf[nx2]);
    STG(vf_h, t + 2, vbuf[nx2]);

    // ---- QK^T swapped: S^T[kpos][q]; lane: q=lr, kpos=ni*16+lg*4+r ----
    f32x4 st[2][4];
#pragma unroll
    for (int mi = 0; mi < 2; ++mi)
#pragma unroll
      for (int ni = 0; ni < 4; ++ni) st[mi][ni] = (f32x4){0.f, 0.f, 0.f, 0.f};
#pragma unroll
    for (int ni = 0; ni < 4; ++ni)
#pragma unroll
      for (int c = 0; c < 4; ++c) {
        bf16x8 kfr = *(const bf16x8*)(kbuf[cur] + (ni * 4 + c) * 1024 + l * 16);
        st[0][ni] = mfma16(kfr, qf[0][c], st[0][ni]);
        st[1][ni] = mfma16(kfr, qf[1][c], st[1][ni]);
      }

    // ---- softmax (log2 domain): per-lane q-row; reduce + 2 shuffles ----
#pragma unroll
    for (int mi = 0; mi < 2; ++mi) {
      float x[4][4];
#pragma unroll
      for (int ni = 0; ni < 4; ++ni)
#pragma unroll
        for (int r = 0; r < 4; ++r)
          x[ni][r] = st[mi][ni][r] * SCALE2 + bf2f(mpre[mi][ni][r]);
      float v = fmaxf(fmaxf(x[0][0], x[0][1]), fmaxf(x[0][2], x[0][3]));
#pragma unroll
      for (int ni = 1; ni < 4; ++ni)
        v = fmaxf(v, fmaxf(fmaxf(x[ni][0], x[ni][1]),
                           fmaxf(x[ni][2], x[ni][3])));
      v = fmaxf(v, __shfl_xor(v, 16));
      v = fmaxf(v, __shfl_xor(v, 32));
      // defer-max (threshold 8 nats = 11.54 log2-units)
      if (__any(v > mrun[mi] + 11.5f)) {
        float mnew = fmaxf(mrun[mi], v);
        float fac = exp2f(mrun[mi] - mnew);
        lrun[mi] *= fac;
        mrun[mi] = mnew;
#pragma unroll
        for (int r = 0; r < 4; ++r) {
          float fr = __shfl(fac, lg * 4 + r);
#pragma unroll
          for (int nd = 0; nd < 8; ++nd) o[mi][nd][r] *= fr;
        }
      }
      // P = exp2(x - m), packed b64 writes into swizzled P tile
      float rs = 0.f;
      char* prow = pbyte + (mi * 16 + lr) * 128;
#pragma unroll
      for (int ni = 0; ni < 4; ++ni) {
        float p0 = exp2f(x[ni][0] - mrun[mi]);
        float p1 = exp2f(x[ni][1] - mrun[mi]);
        float p2 = exp2f(x[ni][2] - mrun[mi]);
        float p3 = exp2f(x[ni][3] - mrun[mi]);
        rs += (p0 + p1) + (p2 + p3);
        uint2 pk;
        pk.x = f2bf(p0) | ((uint32_t)f2bf(p1) << 16);
        pk.y = f2bf(p2) | ((uint32_t)f2bf(p3) << 16);
        *(uint2*)(prow + ((ni * 32 + lg * 8) ^ rswz)) = pk;
      }
      rs += __shfl_xor(rs, 16);
      rs += __shfl_xor(rs, 32);
      lrun[mi] += rs;
    }

    // ---- PV: O += P[32x64] * V[64x128], V frags from LDS ----
#pragma unroll
    for (int ks = 0; ks < 2; ++ks) {
      bf16x8 pf0 = *(const bf16x8*)(pbyte + lr * 128 +
                                    ((ks * 64 + lg * 16) ^ rswz));
      bf16x8 pf1 = *(const bf16x8*)(pbyte + (16 + lr) * 128 +
                                    ((ks * 64 + lg * 16) ^ rswz));
#pragma unroll
      for (int nd = 0; nd < 8; ++nd) {
        bf16x8 vfr = *(const bf16x8*)(vbuf[cur] + (ks * 8 + nd) * 1024 + l * 16);
        o[0][nd] = mfma16(pf0, vfr, o[0][nd]);
        o[1][nd] = mfma16(pf1, vfr, o[1][nd]);
      }
    }

    // ---- counted fence: newest 4 stage-DMAs stay in flight; stage(t+1)
    //      provably retired (issue-order counting). Raw barrier publishes. --
    VMC(4);
    BAR();
    cur = (cur == 2) ? 0 : cur + 1;
  }
#undef STG

  // ---- epilogue: normalize (lrun via shfl), write bf16 A ----
#pragma unroll
  for (int mi = 0; mi < 2; ++mi) {
    float inv[4];
#pragma unroll
    for (int r = 0; r < 4; ++r) inv[r] = 1.0f / __shfl(lrun[mi], lg * 4 + r);
#pragma unroll
    for (int nd = 0; nd < 8; ++nd)
#pragma unroll
      for (int r = 0; r < 4; ++r) {
        int grow = q0 + w * 32 + mi * 16 + lg * 4 + r;
        size_t m = (size_t)b * SQ + grow;
        int col = h * DH + nd * 16 + lr;
        abf[m * HID + col] = f2bf(o[mi][nd][r] * inv[r]);
      }
  }
}

// ---------------------------------------------------------------------------
// Kernel C: C[2048][8192] = A[2048][8192]bf16 · Wt[8192][8192]^T bf16
// 256x256 tile, BK=64, 8 waves (2Mx4N), 8-phase counted-vmcnt schedule,
// T2 swizzle, setprio, XCD-swizzled grid. (Unchanged: 50% MfmaUtil.)
// ---------------------------------------------------------------------------
__global__ __launch_bounds__(512, 2) void k_gemm(const u16* __restrict__ A,
                                                 const u16* __restrict__ Bt,
                                                 float* __restrict__ C) {
  __shared__ char L[131072];
  const int bid = blockIdx.x;
  const int logical = (bid & 7) * 32 + (bid >> 3);
  const int m0 = (logical & 7) * 256;
  const int n0 = (logical >> 3) * 256;
  const int tid = threadIdx.x;
  const int w = tid >> 6, l = tid & 63;
  const int lr = l & 15, lg = l >> 4;
  const int wm = w >> 2, wn = w & 3;   // 2M x 4N

  int srow[2], scol[2];
#pragma unroll
  for (int j = 0; j < 2; ++j) {
    int ch = j * 512 + tid;
    srow[j] = ch >> 3;
    scol[j] = (ch & 7) ^ (srow[j] & 7);
  }

  const char* Ab = (const char*)A;
  const char* Bb = (const char*)Bt;

#define STAGE(gb, row0, tt, dst) do {                                          \
    int kt_ = ((tt) < NT ? (tt) : 0) * 64;                                     \
    _Pragma("unroll")                                                          \
    for (int j_ = 0; j_ < 2; ++j_)                                             \
      gload_lds16((gb) + ((size_t)((row0) + srow[j_]) * 8192 + kt_ +           \
                          scol[j_] * 8) * 2,                                   \
                  (dst) + j_ * 8192 + (w << 10));                              \
  } while (0)

#define LDA(base, hs) do {                                                     \
    _Pragma("unroll")                                                          \
    for (int mi_ = 0; mi_ < 4; ++mi_) {                                        \
      int r_ = wm * 64 + mi_ * 16 + lr;                                        \
      _Pragma("unroll")                                                        \
      for (int ks_ = 0; ks_ < 2; ++ks_)                                        \
        bA[mi_][ks_] = *(const bf16x8*)(L + (base) + (hs) * 16384 + r_ * 128 + \
                        ((ks_ * 64 + lg * 16) ^ ((r_ & 7) << 4)));             \
    }                                                                          \
  } while (0)

#define LDB(dst, base, hs) do {                                                \
    _Pragma("unroll")                                                          \
    for (int ni_ = 0; ni_ < 2; ++ni_) {                                        \
      int r_ = wn * 32 + ni_ * 16 + lr;                                        \
      _Pragma("unroll")                                                        \
      for (int ks_ = 0; ks_ < 2; ++ks_)                                        \
        dst[ni_][ks_] = *(const bf16x8*)(L + (base) + 32768 + (hs) * 16384 +   \
                        r_ * 128 + ((ks_ * 64 + lg * 16) ^ ((r_ & 7) << 4)));  \
    }                                                                          \
  } while (0)

#define MM(mh, nh, BB) do {                                                    \
    __builtin_amdgcn_s_setprio(1);                                             \
    _Pragma("unroll")                                                          \
    for (int mi_ = 0; mi_ < 4; ++mi_)                                          \
      _Pragma("unroll")                                                        \
      for (int ni_ = 0; ni_ < 2; ++ni_)                                        \
        _Pragma("unroll")                                                      \
        for (int ks_ = 0; ks_ < 2; ++ks_)                                      \
          acc[mh][nh][mi_][ni_] =                                              \
              mfma16(bA[mi_][ks_], BB[ni_][ks_], acc[mh][nh][mi_][ni_]);       \
    __builtin_amdgcn_s_setprio(0);                                             \
  } while (0)

  f32x4 acc[2][2][4][2];
#pragma unroll
  for (int a1 = 0; a1 < 2; ++a1)
#pragma unroll
    for (int a2 = 0; a2 < 2; ++a2)
#pragma unroll
      for (int a3 = 0; a3 < 4; ++a3)
#pragma unroll
        for (int a4 = 0; a4 < 2; ++a4)
          acc[a1][a2][a3][a4] = (f32x4){0.f, 0.f, 0.f, 0.f};

  bf16x8 bA[4][2], bB0[2][2], bB1[2][2];

  STAGE(Ab, m0,       0, L + 0);
  STAGE(Bb, n0,       0, L + 32768);
  STAGE(Bb, n0 + 128, 0, L + 49152);
  STAGE(Ab, m0 + 128, 0, L + 16384);
  STAGE(Ab, m0,       1, L + 65536);
  STAGE(Bb, n0,       1, L + 65536 + 32768);
  STAGE(Bb, n0 + 128, 1, L + 65536 + 49152);
  VMC(6);
  BAR();

  for (int t = 0; t < NT; ++t) {
    const int c  = (t & 1) << 16;
    const int cn = c ^ 65536;
    STAGE(Ab, m0 + 128, t + 1, L + cn + 16384);
    LDA(c, 0);
    LDB(bB0, c, 0);
    BAR();
    MM(0, 0, bB0);
    BAR();
    STAGE(Ab, m0, t + 2, L + c + 0);
    LDB(bB1, c, 1);
    BAR();
    MM(0, 1, bB1);
    BAR();
    STAGE(Bb, n0, t + 2, L + c + 32768);
    LDA(c, 1);
    BAR();
    MM(1, 1, bB1);
    BAR();
    STAGE(Bb, n0 + 128, t + 2, L + c + 49152);
    BAR();
    MM(1, 0, bB0);
    VMC(6);
    BAR();
  }
  VMC(0);

#pragma unroll
  for (int mh = 0; mh < 2; ++mh)
#pragma unroll
    for (int nh = 0; nh < 2; ++nh)
#pragma unroll
      for (int mi = 0; mi < 4; ++mi)
#pragma unroll
        for (int ni = 0; ni < 2; ++ni)
#pragma unroll
          for (int rr = 0; rr < 4; ++rr)
            C[(size_t)(m0 + mh * 128 + wm * 64 + mi * 16 + lg * 4 + rr) * 8192 +
              n0 + nh * 128 + wn * 32 + ni * 16 + lr] = acc[mh][nh][mi][ni][rr];
#undef STAGE
#undef LDA
#undef LDB
#undef MM
}

// ---------------------------------------------------------------------------
extern "C" void kernel_launch(void* const* d_in, const int* in_sizes, int n_in,
                              void* d_out, int out_size, void* d_ws, size_t ws_size,
                              hipStream_t stream) {
  const float* xq     = (const float*)d_in[0];
  const float* keys   = (const float*)d_in[1];
  const float* values = (const float*)d_in[2];
  const float* mask   = (const float*)d_in[3];
  const float* wo     = (const float*)d_in[4];
  float* out = (float*)d_out;

  // ws layout (168 MiB):
  //   [0, 32Mi)        A bf16 (attn out, [2048][8192])
  //   [32Mi, 160Mi)    Wt bf16 (wo^T, [8192][8192])
  //   [+4Mi][+4Mi]     Kf / Vf bf16 fragment-major
  // Mask bf16 (4 MiB, wave-fragment-major, pre-scaled by log2e) lives in the
  // LAST 4 MiB of d_out: written by k_prep, read by k_attn, then overwritten
  // by k_gemm's output.
  char* ws = (char*)d_ws;
  u16*  Abf = (u16*)ws;
  u16*  Wt  = (u16*)(ws + 33554432ull);
  char* Kf  = ws + 33554432ull + 134217728ull;
  char* Vf  = Kf + 4194304ull;
  char* Mf  = (char*)d_out + 62914560ull;  // 60 MiB offset

  hipLaunchKernelGGL(k_prep, dim3(19456), dim3(256), 0, stream,
                     wo, Wt, keys, Kf, values, Vf, mask, Mf);
  hipLaunchKernelGGL(k_attn, dim3(512), dim3(512), 0, stream,
                     xq, Kf, Vf, Mf, Abf);
  hipLaunchKernelGGL(k_gemm, dim3(256), dim3(512), 0, stream, Abf, Wt, out);
}